// Round 8
// baseline (440.925 us; speedup 1.0000x reference)
//
#include <hip/hip_runtime.h>
#include <hip/hip_fp16.h>
#include <stdint.h>

// Problem constants (fixed by the reference)
#define N_ 16384
#define M_ 4096
#define D_ 256
#define O_ 256

// Workspace layout (bytes), total ~2.3 MB
#define WS_T    0          // float[N]      exp(sf+ba)     64 KB
#define WS_U    65536      // float[M]      exp(sc)        16 KB
#define WS_R    81920      // float[D]      colsum(Hc)      1 KB
#define WS_WTP  98304      // ushort        Wt packed f16 128 KB
#define WS_BP   229376     // ushort        Hc packed f16   2 MB

typedef float  f32x4  __attribute__((ext_vector_type(4)));
typedef _Float16 half8 __attribute__((ext_vector_type(8)));

// fp32 -> f16 bits (RNE)
__device__ __forceinline__ unsigned short f2h(float f) {
  __half h = __float2half(f);
  unsigned short u;
  __builtin_memcpy(&u, &h, 2);
  return u;
}
// pack two fp32 -> f16x2 bits
__device__ __forceinline__ uint32_t hpack(float a, float b) {
  __half2 h = __floats2half2_rn(a, b);
  uint32_t u;
  __builtin_memcpy(&u, &h, 4);
  return u;
}

// ---------------------------------------------------------------------------
// Merged prep (unchanged): blocks [0,4096) rowdot(Hf)->tv, [4096,5120)
// rowdot(Hc)->uv, [5120,5376) hc_pack, [5376,5408) wt_pack.
__global__ __launch_bounds__(256) void prep_kernel(
    const float* __restrict__ Hf, const float* __restrict__ Hc,
    const float* __restrict__ wa, const float* __restrict__ ba,
    const float* __restrict__ Wt, float* __restrict__ tv,
    float* __restrict__ uv, unsigned short* __restrict__ BP,
    unsigned short* __restrict__ WtP, float* __restrict__ Rv) {
  __shared__ float tile[64][65];
  __shared__ float red[4][64];
  int b = blockIdx.x;
  int t = threadIdx.x;
  if (b < 5120) {
    int wv = t >> 6, lane = t & 63;
    const float* X; const float* w; const float* bias; float* outv; int row;
    if (b < 4096) { X = Hf; w = wa;      bias = ba;      outv = tv; row = b * 4 + wv; }
    else          { X = Hc; w = wa + D_; bias = nullptr; outv = uv; row = (b - 4096) * 4 + wv; }
    const float4* x4 = (const float4*)(X + (size_t)row * D_);
    const float4* w4 = (const float4*)w;
    float4 xa = x4[lane], wa4 = w4[lane];
    float s = xa.x * wa4.x + xa.y * wa4.y + xa.z * wa4.z + xa.w * wa4.w;
#pragma unroll
    for (int off = 32; off > 0; off >>= 1) s += __shfl_xor(s, off);
    if (lane == 0) outv[row] = expf(s + (bias ? bias[0] : 0.0f));
  } else if (b < 5376) {
    int bb = b - 5120;
    int bk = bb >> 2;   // 64 tiles along M (k)
    int bc = bb & 3;    // 4 tiles along D (col)
    int k0 = bk * 64, col0 = bc * 64;
    int lane = t & 63, wv = t >> 6;
    int m = lane & 15, q = lane >> 4;
    float colsum = 0.0f;
#pragma unroll
    for (int i = 0; i < 16; ++i) {
      int e = t + 256 * i;
      int kk = e >> 6, cc = e & 63;
      float v = Hc[(size_t)(k0 + kk) * D_ + col0 + cc];
      tile[kk][cc] = v;
      colsum += v;
    }
    red[wv][t & 63] = colsum;
    __syncthreads();
    if (t < 64)
      atomicAdd(&Rv[col0 + t], red[0][t] + red[1][t] + red[2][t] + red[3][t]);
#pragma unroll
    for (int t8 = 0; t8 < 2; ++t8) {
      int tile_id = t8 * 4 + wv;
      int sub = tile_id >> 2, g = tile_id & 3;
      int kgg = bk * 2 + sub;
      int cgg = bc * 4 + g;
      unsigned short v8[8];
#pragma unroll
      for (int j = 0; j < 8; ++j)
        v8[j] = f2h(tile[sub * 32 + q * 8 + j][g * 16 + m]);
      *(uint4*)(BP + ((size_t)(kgg * 16 + cgg) * 64 + lane) * 8) = *(uint4*)v8;
    }
  } else {
    int tt = (b - 5376) * 256 + t;    // 0..8191
    int lane = tt & 63, cg = (tt >> 6) & 15, kg = tt >> 10;
    int m = lane & 15, q = lane >> 4;
    const float* src = Wt + (size_t)(cg * 16 + m) * D_ + kg * 32 + q * 8;
    float4 w0 = *(const float4*)src, w1 = *(const float4*)(src + 4);
    unsigned short v8[8];
    v8[0] = f2h(w0.x); v8[1] = f2h(w0.y); v8[2] = f2h(w0.z); v8[3] = f2h(w0.w);
    v8[4] = f2h(w1.x); v8[5] = f2h(w1.y); v8[6] = f2h(w1.z); v8[7] = f2h(w1.w);
    *(uint4*)(WtP + (size_t)tt * 8) = *(uint4*)v8;
  }
}

// ---------------------------------------------------------------------------
// A-fragment: af = f16(adj) * (t*u - 1). adj is exactly 0/1 in f16, so this
// equals the old masked fragment bit-for-bit (0*w = +/-0, 1*w = w) with ZERO
// bit machinery: 4 pk_fma + 4 pk_mul per 8 elements.
__device__ __forceinline__ half8 buildA(half8 a, __half2 th,
                                        const __half2* up, __half2 mone) {
  uint32_t ai[4], ro[4];
  __builtin_memcpy(ai, &a, 16);
#pragma unroll
  for (int k = 0; k < 4; ++k) {
    __half2 w2 = __hfma2(th, up[k], mone);
    __half2 av;
    __builtin_memcpy(&av, &ai[k], 4);
    __half2 r = __hmul2(av, w2);
    __builtin_memcpy(&ro[k], &r, 4);
  }
  half8 res;
  __builtin_memcpy(&res, ro, 16);
  return res;
}

// issue global loads of one adj chunk slice (this thread: row srow, 16 cols)
#define LOADS(KB)                                                             \
  _Pragma("unroll")                                                           \
  for (int p = 0; p < 4; ++p)                                                 \
    na[p] = *(const float4*)(arow + (KB) + p * 64 + t15 * 4);

// convert na -> f16 A-tile in LDS[BUF]; accumulate su/sc for Lsum (exact f32)
#define TAIL(BUF, KB)                                                         \
  _Pragma("unroll")                                                           \
  for (int p = 0; p < 4; ++p) {                                               \
    int col = (KB) + p * 64 + t15 * 4;                                        \
    float4 u4 = *(const float4*)&u_lds[col];                                  \
    su = fmaf(na[p].x, u4.x, su); su = fmaf(na[p].y, u4.y, su);               \
    su = fmaf(na[p].z, u4.z, su); su = fmaf(na[p].w, u4.w, su);               \
    sc += (na[p].x + na[p].y) + (na[p].z + na[p].w);                          \
    uint2 hv;                                                                 \
    hv.x = hpack(na[p].x, na[p].y);                                           \
    hv.y = hpack(na[p].z, na[p].w);                                           \
    *(uint2*)&A_lds[BUF][srow][p * 64 + t15 * 4] = hv;                        \
  }

// compute one chunk (8 kg): per kg, 2 A-frags (rt0/rt1) from LDS, 2 B-frags
// (this wave's 2 cg) from L2, 4 MFMAs. Wave = colq only -> B read once/block.
#define COMPUTE(C, BUF)                                                       \
  _Pragma("unroll")                                                           \
  for (int kgl = 0; kgl < 8; ++kgl) {                                         \
    int kg = (C) * 8 + kgl;                                                   \
    const unsigned short* bp = BP + ((size_t)(kg * 16 + w * 2)) * 512 + (size_t)lane * 8; \
    half8 bf0 = *(const half8*)(bp);                                          \
    half8 bf1 = *(const half8*)(bp + 512);                                    \
    uint4 uu = *(const uint4*)&u_h2[kg * 16 + q * 4];                         \
    __half2 up[4];                                                            \
    __builtin_memcpy(up, &uu, 16);                                            \
    half8 a0 = *(const half8*)&A_lds[BUF][m][kgl * 32 + q * 8];               \
    half8 a1 = *(const half8*)&A_lds[BUF][16 + m][kgl * 32 + q * 8];          \
    half8 af0 = buildA(a0, th0, up, mone);                                    \
    half8 af1 = buildA(a1, th1, up, mone);                                    \
    acc[0][0] = __builtin_amdgcn_mfma_f32_16x16x32_f16(af0, bf0, acc[0][0], 0, 0, 0); \
    acc[0][1] = __builtin_amdgcn_mfma_f32_16x16x32_f16(af0, bf1, acc[0][1], 0, 0, 0); \
    acc[1][0] = __builtin_amdgcn_mfma_f32_16x16x32_f16(af1, bf0, acc[1][0], 0, 0, 0); \
    acc[1][1] = __builtin_amdgcn_mfma_f32_16x16x32_f16(af1, bf1, acc[1][1], 0, 0, 0); \
  }

// ---------------------------------------------------------------------------
// Mega kernel v6: adj staged as f16 A-matrix (classical GEMM structure).
// R5-R7 lesson: the bit pipeline (ballot -> bits LDS -> bfe/bfi masks) was
// the stall source, not the schedule. adj in {0,1} is exact in f16, so
// af = f16(adj)*(t*u-1) == the masked fragment, and staging is a plain
// coalesced f32->f16 copy (su/sc Lsum fmas folded in).
// Block: 32 rows, 512 thr, 8 waves = 8 colq (32 cols each, both row-tiles,
// FULL K) -> B read exactly once per block; no split-K -> no Cred pass,
// acc -> attn in-register. Chunk pipeline: LOADS(c+1) / COMPUTE(c) /
// TAIL(c+1) / barrier, A-tile double-buffered.
// LDS: A dbuf 2x32x272 f16 = 34.8K | u f32 16K | u_h2 8K | Lsum 128B
//    = 59.5 KB -> 2 blocks/CU.
__global__ __launch_bounds__(512, 4) void mega_kernel(
    const float* __restrict__ adj, const unsigned short* __restrict__ BP,
    const float* __restrict__ tv, const float* __restrict__ uv,
    const float* __restrict__ Rv, const float* __restrict__ Hf,
    const unsigned short* __restrict__ WtP, const float* __restrict__ bt,
    float* __restrict__ out) {
  __shared__ __align__(16) char smem[59520];
  unsigned short (*A_lds)[32][272] = (unsigned short (*)[32][272])(smem); // 34816 B
  float* u_lds = (float*)(smem + 34816);                              // 16384 B
  uint32_t* u_h2 = (uint32_t*)(smem + 51200);                         //  8192 B
  float* Lsum_lds = (float*)(smem + 59392);                           //   128 B
  unsigned short (*attn)[264] = (unsigned short (*)[264])(smem);      // 16896 B (aliases A_lds, dead by then)

  int tid = threadIdx.x;
  int w = tid >> 6, lane = tid & 63;
  int q = lane >> 4, m = lane & 15;
  int srow = tid >> 4, t15 = tid & 15;   // staging: row srow, 16 thr/row
  int i0 = blockIdx.x * 32;

  const float* arow = adj + ((size_t)i0 + srow) * M_;
  float su = 0.f, sc = 0.f;
  float4 na[4];

  // chunk-0 loads issued first (overlap the u-table fill)
  LOADS(0)

  // u: f32 copy (Lsum fmas) + packed half2 copy (w-pair builds)
  for (int i = tid; i < M_ / 2; i += 512) {
    float2 u2 = *(const float2*)(uv + 2 * i);
    u_lds[2 * i] = u2.x; u_lds[2 * i + 1] = u2.y;
    u_h2[i] = hpack(u2.x, u2.y);
  }

  __half2 th0 = __float2half2_rn(tv[i0 + m]);
  __half2 th1 = __float2half2_rn(tv[i0 + 16 + m]);
  const __half2 mone = __float2half2_rn(-1.0f);

  f32x4 acc[2][2];
#pragma unroll
  for (int s = 0; s < 2; ++s)
#pragma unroll
    for (int n = 0; n < 2; ++n) acc[s][n] = (f32x4){0.f, 0.f, 0.f, 0.f};

  __syncthreads();   // u ready
  TAIL(0, 0)         // chunk 0 -> buf 0
  __syncthreads();   // A buf0 ready

#pragma unroll 1
  for (int c = 0; c < 16; ++c) {
    if (c < 15) { LOADS((c + 1) * 256) }          // prefetch next chunk
    COMPUTE(c, c & 1)                             // MFMA on current A-tile
    if (c < 15) { TAIL((c + 1) & 1, (c + 1) * 256) }
    __syncthreads();
  }

  // ---- Lsum: reduce 16-lane groups (threads of one staging row)
#pragma unroll
  for (int off = 1; off < 16; off <<= 1) {
    su += __shfl_xor(su, off);
    sc += __shfl_xor(sc, off);
  }
  if (t15 == 0)
    Lsum_lds[srow] = tv[i0 + srow] * su - sc;
  __syncthreads();

  // ---- attn = (acc + R)/(Lsum + M) + Hf -> f16 LDS (in-register, no Cred)
  {
    float rv0 = Rv[w * 32 + m];
    float rv1 = Rv[w * 32 + 16 + m];
#pragma unroll
    for (int rt = 0; rt < 2; ++rt)
#pragma unroll
      for (int r = 0; r < 4; ++r) {
        int row = rt * 16 + q * 4 + r;      // C/D: row=(lane>>4)*4+reg
        float invL = 1.0f / (Lsum_lds[row] + (float)M_);
        size_t grow = (size_t)i0 + row;
        float h0 = Hf[grow * D_ + w * 32 + m];
        float h1 = Hf[grow * D_ + w * 32 + 16 + m];
        attn[row][w * 32 + m]      = f2h(fmaf(acc[rt][0][r] + rv0, invL, h0));
        attn[row][w * 32 + 16 + m] = f2h(fmaf(acc[rt][1][r] + rv1, invL, h1));
      }
  }
  __syncthreads();

  // ---- out = relu(attn @ Wt^T + bt). 8 waves = 2 rt2 x 4 cq.
  {
    int rt2 = w & 1, cq = w >> 1;       // rows rt2*16.., cols cq*64..
    f32x4 facc[4];
#pragma unroll
    for (int n = 0; n < 4; ++n) facc[n] = (f32x4){0.f, 0.f, 0.f, 0.f};
    const unsigned short* wwave = WtP + (size_t)(cq * 4) * 512 + (size_t)lane * 8;
#pragma unroll
    for (int kf = 0; kf < 8; ++kf) {
      half8 af = *(const half8*)&attn[rt2 * 16 + m][kf * 32 + q * 8];
#pragma unroll
      for (int n = 0; n < 4; ++n) {
        half8 bf = *(const half8*)(wwave + ((size_t)kf * 16 + n) * 512);
        facc[n] = __builtin_amdgcn_mfma_f32_16x16x32_f16(af, bf, facc[n], 0, 0, 0);
      }
    }
#pragma unroll
    for (int n = 0; n < 4; ++n) {
      int col = cq * 64 + n * 16 + m;
      float b = bt[col];
#pragma unroll
      for (int r = 0; r < 4; ++r) {
        size_t row = (size_t)i0 + rt2 * 16 + q * 4 + r;
        out[row * O_ + col] = fmaxf(facc[n][r] + b, 0.0f);
      }
    }
  }
}

// ---------------------------------------------------------------------------
extern "C" void kernel_launch(void* const* d_in, const int* in_sizes, int n_in,
                              void* d_out, int out_size, void* d_ws, size_t ws_size,
                              hipStream_t stream) {
  const float* Hf  = (const float*)d_in[0];  // [N,D]
  const float* Hc  = (const float*)d_in[1];  // [M,D]
  const float* adj = (const float*)d_in[2];  // [N,M]
  const float* wa  = (const float*)d_in[3];  // [2D]
  const float* ba  = (const float*)d_in[4];  // [1]
  const float* Wt  = (const float*)d_in[5];  // [O,D]
  const float* bt  = (const float*)d_in[6];  // [O]
  float* out = (float*)d_out;

  char* ws = (char*)d_ws;
  float* tv   = (float*)(ws + WS_T);
  float* uv   = (float*)(ws + WS_U);
  float* Rv   = (float*)(ws + WS_R);
  unsigned short* WtP = (unsigned short*)(ws + WS_WTP);
  unsigned short* BP  = (unsigned short*)(ws + WS_BP);

  hipMemsetAsync(Rv, 0, D_ * sizeof(float), stream);  // atomic target

  prep_kernel<<<5408, 256, 0, stream>>>(Hf, Hc, wa, ba, Wt, tv, uv, BP, WtP, Rv);
  mega_kernel<<<512, 512, 0, stream>>>(adj, BP, tv, uv, Rv, Hf, WtP, bt, out);
}